// Round 12
// baseline (276.495 us; speedup 1.0000x reference)
//
#include <hip/hip_runtime.h>
#include <hip/hip_bf16.h>
#include <math.h>

#define SEQ 2048
#define DM  2048
#define NH  16
#define HD  128
#define SCALE 0.08838834764831845f

typedef __bf16 bf16_t;
typedef __bf16 bf16x8 __attribute__((ext_vector_type(8)));
typedef __bf16 bf16x4 __attribute__((ext_vector_type(4)));
typedef float  f32x4  __attribute__((ext_vector_type(4)));
typedef int    i32x4  __attribute__((ext_vector_type(4)));

typedef const __attribute__((address_space(1))) void* gas_ptr;
typedef __attribute__((address_space(3))) void* las_ptr;

__device__ __forceinline__ void gload_lds16(const void* g, void* l) {
    __builtin_amdgcn_global_load_lds((gas_ptr)g, (las_ptr)l, 16, 0, 0);
}

__device__ __forceinline__ f32x4 mfma_bf16(bf16x8 a, bf16x8 b, f32x4 c) {
    return __builtin_amdgcn_mfma_f32_16x16x32_bf16(a, b, c, 0, 0, 0);
}

__device__ __forceinline__ unsigned cvtpk_bf16(float lo, float hi) {
    unsigned d;
    asm("v_cvt_pk_bf16_f32 %0, %1, %2" : "=v"(d) : "v"(lo), "v"(hi));
    return d;
}

// LDS tile with 64 bf16 per row (128B): chunk (16B) XOR-swizzled by row&7
__device__ __forceinline__ bf16x8 read_frag64(const bf16_t* lds, int row, int k) {
    int chunk = (k >> 3) ^ (row & 7);
    return *(const bf16x8*)(lds + row * 64 + chunk * 8);
}
// LDS tile with 128 bf16 per row (256B): low 3 chunk bits swizzled
__device__ __forceinline__ bf16x8 read_frag128(const bf16_t* lds, int row, int k) {
    int chunk = k >> 3;
    chunk = (chunk & 8) | ((chunk ^ row) & 7);
    return *(const bf16x8*)(lds + row * 128 + chunk * 8);
}
// K-slab layout [256 rows][32 bf16], 16B slot-swizzled: phys j = kj ^ ((row>>1)&3)
__device__ __forceinline__ bf16x8 read_slab(const bf16_t* sl, int row, int g) {
    int j = g ^ ((row >> 1) & 3);
    return *(const bf16x8*)(sl + row * 32 + j * 8);
}

// ---------------- fp32 -> bf16 conversion (4 arrays of 2048*2048) -------------
__global__ __launch_bounds__(256) void cvt5(
    const float* __restrict__ s0, const float* __restrict__ s1,
    const float* __restrict__ s2, const float* __restrict__ s3,
    const float* __restrict__ s4,
    bf16_t* __restrict__ d0, bf16_t* __restrict__ d1, bf16_t* __restrict__ d2,
    bf16_t* __restrict__ d3, bf16_t* __restrict__ d4)
{
    int which = blockIdx.y;
    const float* s; bf16_t* d;
    switch (which) {
        case 0: s = s0; d = d0; break;
        case 1: s = s1; d = d1; break;
        case 2: s = s2; d = d2; break;
        case 3: s = s3; d = d3; break;
        default: s = s4; d = d4; break;
    }
    size_t idx = ((size_t)blockIdx.x * 256 + threadIdx.x) * 4;
    float4 v = *(const float4*)(s + idx);
    bf16x4 o = { (bf16_t)v.x, (bf16_t)v.y, (bf16_t)v.z, (bf16_t)v.w };
    *(bf16x4*)(d + idx) = o;
}

// ---------------- pipelined QKV GEMM: 256x256, BK=64, merged double-phases ---
// grid (24 bny, 8 bm): XCD = linear%8 = bny%8 -> 3 B-panels L2-resident per XCD
#define BARX() asm volatile("s_barrier" ::: "memory")
#define VMW8 asm volatile("s_waitcnt vmcnt(8)" ::: "memory")
#define VMW4 asm volatile("s_waitcnt vmcnt(4)" ::: "memory")
#define VMW0 asm volatile("s_waitcnt vmcnt(0)" ::: "memory")
#define NOGATE

__global__ __launch_bounds__(512, 2) void qkv_pipe(
    const bf16_t* __restrict__ A,
    const bf16_t* __restrict__ B0, const bf16_t* __restrict__ B1,
    const bf16_t* __restrict__ B2,
    bf16_t* __restrict__ Oq, bf16_t* __restrict__ Ok, bf16_t* __restrict__ Ov,
    const float* __restrict__ fcos, const float* __restrict__ fsin)
{
    __shared__ bf16_t lds[65536];   // 128 KB

    const int tid = threadIdx.x;
    const int lane = tid & 63;
    const int w = tid >> 6;
    const int wm = w >> 2;           // 0..1
    const int wn = w & 3;            // 0..3
    const int g4 = lane >> 4, r15 = lane & 15;

    const int bm = blockIdx.y;       // 0..7
    const int bny = blockIdx.x;      // 0..23
    const int sel = bny >> 3;
    const int bnl = bny & 7;
    const bf16_t* Bp = (sel == 0) ? B0 : (sel == 1) ? B1 : B2;

    const size_t arow0 = (size_t)bm * 256;
    const size_t brow0 = (size_t)bnl * 256;

    const int row0 = tid >> 2;                    // c0 row (c1 row = row0+128)
    const int kj0  = (tid & 3) ^ ((row0 >> 1) & 3);
    const bf16_t* pA = A  + (arow0 + row0) * DM + kj0 * 8;
    const bf16_t* pB = Bp + (brow0 + row0) * DM + kj0 * 8;
    char* ldsb = (char*)lds;
    const int off0 = tid * 16;
    const int off1 = 8192 + tid * 16;

    #define STAGE_HT(S) do { if ((S) < 128) {                                   \
        const int T_ = (S) >> 2, a_ = (S) & 3;                                  \
        const int ko_ = T_ * 64 + ((a_ >> 1) << 5);                             \
        char* dst_ = ldsb + (((T_ & 1) << 16) | ((a_ & 1) << 15) | ((a_ >> 1) << 14)); \
        const bf16_t* s0_ = (a_ & 1) ? pB : pA;                                 \
        gload_lds16(s0_ + ko_, dst_ + off0);                                    \
        gload_lds16(s0_ + 128 * DM + ko_, dst_ + off1);                         \
    } } while (0)

    const bf16_t* b0A0 = lds;
    const bf16_t* b0A1 = lds + 8192;
    const bf16_t* b0B0 = lds + 16384;
    const bf16_t* b0B1 = lds + 24576;
    const bf16_t* b1A0 = lds + 32768;
    const bf16_t* b1A1 = lds + 40960;
    const bf16_t* b1B0 = lds + 49152;
    const bf16_t* b1B1 = lds + 57344;

    f32x4 acc[8][4] = {};

    #define PHASE2(ASL, BSL, S1, S2, GATE)                                      \
    {                                                                           \
        GATE;                                                                   \
        _Pragma("unroll")                                                       \
        for (int k = 0; k < 8; ++k)                                             \
            af[k] = read_slab((ASL), wm * 128 + k * 16 + r15, g4);              \
        _Pragma("unroll")                                                       \
        for (int n = 0; n < 4; ++n)                                             \
            bfr[n] = read_slab((BSL), wn * 64 + n * 16 + r15, g4);              \
        STAGE_HT(S1);                                                           \
        STAGE_HT(S2);                                                           \
        BARX();                                                                 \
        __builtin_amdgcn_s_setprio(1);                                          \
        _Pragma("unroll")                                                       \
        for (int k = 0; k < 8; ++k)                                             \
            _Pragma("unroll")                                                   \
            for (int n = 0; n < 4; ++n)                                         \
                acc[k][n] = mfma_bf16(af[k], bfr[n], acc[k][n]);                \
        __builtin_amdgcn_s_setprio(0);                                          \
        BARX();                                                                 \
    }

    STAGE_HT(0); STAGE_HT(1); STAGE_HT(2); STAGE_HT(3); STAGE_HT(4); STAGE_HT(5);
    VMW8;
    BARX();

    for (int i = 0; i < 15; ++i) {
        const int s0 = 6 + i * 8;
        bf16x8 af[8], bfr[4];
        PHASE2(b0A0, b0B0, s0 + 0, s0 + 1, VMW8)
        PHASE2(b0A1, b0B1, s0 + 2, s0 + 3, VMW8)
        PHASE2(b1A0, b1B0, s0 + 4, s0 + 5, VMW8)
        PHASE2(b1A1, b1B1, s0 + 6, s0 + 7, VMW8)
    }
    {   // final iter: stages 126,127 real, rest no-op; drain 8 -> 4 -> 0
        bf16x8 af[8], bfr[4];
        PHASE2(b0A0, b0B0, 126, 127, VMW8)
        PHASE2(b0A1, b0B1, 200, 200, VMW8)
        PHASE2(b1A0, b1B0, 200, 200, VMW4)
        PHASE2(b1A1, b1B1, 200, 200, VMW0)
    }
    #undef PHASE2
    #undef STAGE_HT

    const int r0 = bm * 256 + wm * 128;
    const int c0 = bnl * 256 + wn * 64;

    if (sel == 2) {
        #pragma unroll
        for (int m = 0; m < 8; ++m) {
            int rowb = r0 + m * 16 + g4 * 4;
            #pragma unroll
            for (int n = 0; n < 4; ++n) {
                int col = c0 + n * 16 + r15;
                bf16x4 pk = { (bf16_t)acc[m][n][0], (bf16_t)acc[m][n][1],
                              (bf16_t)acc[m][n][2], (bf16_t)acc[m][n][3] };
                *(bf16x4*)&Ov[(size_t)col * SEQ + rowb] = pk;
            }
        }
    } else {
        bf16_t* dst = (sel == 0) ? Oq : Ok;
        #pragma unroll
        for (int m = 0; m < 8; ++m) {
            int rowb = r0 + m * 16 + g4 * 4;
            #pragma unroll
            for (int n = 0; n < 4; ++n) {
                int col = c0 + n * 16 + r15;
                int f = (col & (HD - 1)) >> 1;
                float sgn = (col & 1) ? 1.0f : -1.0f;
                #pragma unroll
                for (int r = 0; r < 4; ++r) {
                    float mine = acc[m][n][r];
                    float other = __shfl_xor(mine, 1);
                    float cc = fcos[(rowb + r) * (HD / 2) + f];
                    float ss = fsin[(rowb + r) * (HD / 2) + f];
                    float o = mine * cc + sgn * other * ss;
                    dst[(size_t)(rowb + r) * DM + col] = (bf16_t)o;
                }
            }
        }
    }
}

// ---------------- final projection GEMM with fused combine --------------------
// A-tile staged from PARTIAL attention outputs: A = (Op0 + Op1) / (L0+L1+eps)
// B-tile staged directly from fp32 Wo (cvt on the fly). 128x64 tile.
__global__ __launch_bounds__(256) void gemm_fin(
    const bf16_t* __restrict__ Op, const float* __restrict__ Lp,
    const float* __restrict__ Wo, float* __restrict__ Of)
{
    __shared__ bf16_t lA[128 * 64];
    __shared__ bf16_t lB[64 * 64];

    const int tid = threadIdx.x;
    const int lane = tid & 63;
    const int w = tid >> 6;
    const int wm = w >> 1, wn = w & 1;
    const int g = lane >> 4, r15 = lane & 15;

    const int bm = blockIdx.x;   // 0..15
    const int bn = blockIdx.y;   // 0..31

    f32x4 acc[4][2] = {};

    const int arow0 = bm * 128;
    const int brow0 = bn * 64;

    for (int kt = 0; kt < DM / 64; ++kt) {
        const int k0 = kt * 64;
        // A-tile: combine the two key-split partials on the fly
        #pragma unroll
        for (int i = 0; i < 4; ++i) {
            int c = i * 256 + tid;
            int row = c >> 3;
            int ck = (c ^ row) & 7;          // logical chunk for phys slot c&7
            int gr = arow0 + row;
            int gc = k0 + ck * 8;
            int h = gc >> 7;
            float L = Lp[(size_t)h * SEQ + gr] + Lp[(size_t)(NH + h) * SEQ + gr] + 1e-6f;
            float inv = 1.0f / L;
            bf16x8 v0 = *(const bf16x8*)(Op + (size_t)gr * DM + gc);
            bf16x8 v1 = *(const bf16x8*)(Op + (size_t)SEQ * DM + (size_t)gr * DM + gc);
            bf16x8 o;
            #pragma unroll
            for (int j = 0; j < 8; ++j)
                o[j] = (bf16_t)(((float)v0[j] + (float)v1[j]) * inv);
            *(bf16x8*)((char*)lA + c * 16) = o;
        }
        // B-tile: Wo fp32 -> bf16
        #pragma unroll
        for (int i = 0; i < 2; ++i) {
            int c = i * 256 + tid;
            int row = c >> 3;
            int ck = (c ^ row) & 7;
            const float* src = Wo + (size_t)(brow0 + row) * DM + k0 + ck * 8;
            float4 f0 = *(const float4*)(src);
            float4 f1 = *(const float4*)(src + 4);
            bf16x8 o = { (bf16_t)f0.x, (bf16_t)f0.y, (bf16_t)f0.z, (bf16_t)f0.w,
                         (bf16_t)f1.x, (bf16_t)f1.y, (bf16_t)f1.z, (bf16_t)f1.w };
            *(bf16x8*)((char*)lB + c * 16) = o;
        }
        __syncthreads();
        #pragma unroll
        for (int kk = 0; kk < 2; ++kk) {
            bf16x8 af[4], bfr[2];
            #pragma unroll
            for (int m = 0; m < 4; ++m)
                af[m] = read_frag64(lA, wm * 64 + m * 16 + r15, kk * 32 + g * 8);
            #pragma unroll
            for (int n = 0; n < 2; ++n)
                bfr[n] = read_frag64(lB, wn * 32 + n * 16 + r15, kk * 32 + g * 8);
            #pragma unroll
            for (int m = 0; m < 4; ++m)
                #pragma unroll
                for (int n = 0; n < 2; ++n)
                    acc[m][n] = mfma_bf16(af[m], bfr[n], acc[m][n]);
        }
        __syncthreads();
    }

    const int r0 = bm * 128 + wm * 64;
    const int c0 = bn * 64 + wn * 32;
    #pragma unroll
    for (int m = 0; m < 4; ++m) {
        int rowb = r0 + m * 16 + g * 4;
        #pragma unroll
        for (int n = 0; n < 2; ++n) {
            int col = c0 + n * 16 + r15;
            #pragma unroll
            for (int r = 0; r < 4; ++r)
                Of[(size_t)(rowb + r) * DM + col] = acc[m][n][r];
        }
    }
}

// ---------------- attention v7: QBLK=128, key-split 2, 2 blocks/CU -----------
// grid (16 qb, 16 h, 2 sp) = 512 blocks, 256 thr = 4 waves, wave = 32 q-rows
// (u in {0,1}). Each block handles keys [sp*1024, sp*1024+1024) = 16 j-iters,
// writes PARTIAL O (bf16) + PARTIAL L (f32); gemm_fin combines while staging.
__global__ __launch_bounds__(256, 2) void attn_k6(
    const bf16_t* __restrict__ Q, const bf16_t* __restrict__ Kb,
    const bf16_t* __restrict__ Vt, bf16_t* __restrict__ Op,
    float* __restrict__ Lp)
{
    __shared__ bf16_t lk[2 * 64 * 128];   // K tiles (double buffer)
    __shared__ bf16_t lv[2 * 128 * 64];   // V^T tiles (double buffer)

    const int tid = threadIdx.x;          // 0..255
    const int lane = tid & 63;
    const int w = tid >> 6;               // 0..3: q-rows w*32 .. w*32+31
    const int g = lane >> 4, r15 = lane & 15;
    const int qb = blockIdx.x;            // 0..15
    const int h = blockIdx.y;             // 0..15
    const int sp = blockIdx.z;            // 0..1
    const int j0 = sp * 16;

    const int lo = g & 1, hb = g >> 1;
    const int e_src = (lo << 5) + r15;
    const int o_src = e_src + 16;
    const int sA = hb ? o_src : e_src;
    const int sB = hb ? e_src : o_src;

    // Q fragments: qf[u][ks] for q = qb*128 + w*32 + u*16 + r15
    bf16x8 qf[2][4];
    #pragma unroll
    for (int u = 0; u < 2; ++u) {
        const bf16_t* qrow = Q + (size_t)(qb * 128 + w * 32 + u * 16 + r15) * DM + h * HD + g * 8;
        #pragma unroll
        for (int ks = 0; ks < 4; ++ks)
            qf[u][ks] = *(const bf16x8*)(qrow + ks * 32);
    }

    f32x4 oacc[2][8] = {};
    float Lsum[2] = {0.f, 0.f};

    #define STAGE_KV(JJ, BUF)                                                     \
    {                                                                             \
        _Pragma("unroll")                                                         \
        for (int i = 0; i < 4; ++i) {                                             \
            int c = i * 256 + tid;                                                \
            int row = c >> 4, ckl = c & 15;                                       \
            int ck = (ckl & 8) | ((ckl ^ row) & 7);                               \
            const bf16_t* gk = Kb + (size_t)((JJ) * 64 + row) * DM + h * HD + ck * 8; \
            gload_lds16(gk, (char*)lk + (BUF) * 16384 + (i * 256 + w * 64) * 16); \
        }                                                                         \
        _Pragma("unroll")                                                         \
        for (int i = 0; i < 4; ++i) {                                             \
            int c = i * 256 + tid;                                                \
            int row = c >> 3;                                                     \
            int ck = (c ^ row) & 7;                                               \
            const bf16_t* gv = Vt + (size_t)(h * HD + row) * SEQ + (JJ) * 64 + ck * 8; \
            gload_lds16(gv, (char*)lv + (BUF) * 16384 + (i * 256 + w * 64) * 16); \
        }                                                                         \
    }

    STAGE_KV(j0, 0);
    asm volatile("s_waitcnt vmcnt(0)" ::: "memory");
    __builtin_amdgcn_s_barrier();

    for (int jj = 0; jj < 16; ++jj) {
        const int cur = jj & 1;
        const bf16_t* lkc = lk + cur * 8192;
        const bf16_t* lvc = lv + cur * 8192;
        if (jj < 15) STAGE_KV(j0 + jj + 1, cur ^ 1);

        // ---- QK^T swapped; kf shared across u
        f32x4 sacc[2][4] = {};
        __builtin_amdgcn_s_setprio(1);
        #pragma unroll
        for (int ks = 0; ks < 4; ++ks) {
            #pragma unroll
            for (int n = 0; n < 4; ++n) {
                bf16x8 kf = read_frag128(lkc, n * 16 + r15, ks * 32 + g * 8);
                sacc[0][n] = mfma_bf16(kf, qf[0][ks], sacc[0][n]);
                sacc[1][n] = mfma_bf16(kf, qf[1][ks], sacc[1][n]);
            }
        }
        __builtin_amdgcn_s_setprio(0);

        bf16x8 pa0[2], pa1[2];
        #pragma unroll
        for (int u = 0; u < 2; ++u) {
            float mx0 = fmaxf(fmaxf(sacc[u][0][0], sacc[u][0][1]), fmaxf(sacc[u][0][2], sacc[u][0][3]));
            float mx1 = fmaxf(fmaxf(sacc[u][1][0], sacc[u][1][1]), fmaxf(sacc[u][1][2], sacc[u][1][3]));
            float mx2 = fmaxf(fmaxf(sacc[u][2][0], sacc[u][2][1]), fmaxf(sacc[u][2][2], sacc[u][2][3]));
            float mx3 = fmaxf(fmaxf(sacc[u][3][0], sacc[u][3][1]), fmaxf(sacc[u][3][2], sacc[u][3][3]));
            float mx = fmaxf(fmaxf(mx0, mx1), fmaxf(mx2, mx3));
            mx = fmaxf(mx, __shfl_xor(mx, 16));
            mx = fmaxf(mx, __shfl_xor(mx, 32));

            float p[4][4];
            float ls = 0.f;
            #pragma unroll
            for (int n = 0; n < 4; ++n)
                #pragma unroll
                for (int r = 0; r < 4; ++r) {
                    float pv = __expf((sacc[u][n][r] - mx) * SCALE);
                    p[n][r] = pv;
                    ls += pv;
                }
            Lsum[u] += ls;

            unsigned D00 = cvtpk_bf16(p[0][0], p[0][1]), D01 = cvtpk_bf16(p[0][2], p[0][3]);
            unsigned D10 = cvtpk_bf16(p[1][0], p[1][1]), D11 = cvtpk_bf16(p[1][2], p[1][3]);
            unsigned D20 = cvtpk_bf16(p[2][0], p[2][1]), D21 = cvtpk_bf16(p[2][2], p[2][3]);
            unsigned D30 = cvtpk_bf16(p[3][0], p[3][1]), D31 = cvtpk_bf16(p[3][2], p[3][3]);

            unsigned r0 = __shfl((int)(lo ? D10 : D00), sA);
            unsigned r1 = __shfl((int)(lo ? D11 : D01), sA);
            unsigned r2 = __shfl((int)(lo ? D00 : D10), sB);
            unsigned r3 = __shfl((int)(lo ? D01 : D11), sB);
            unsigned r4 = __shfl((int)(lo ? D30 : D20), sA);
            unsigned r5 = __shfl((int)(lo ? D31 : D21), sA);
            unsigned r6 = __shfl((int)(lo ? D20 : D30), sB);
            unsigned r7 = __shfl((int)(lo ? D21 : D31), sB);
            i32x4 w0, w1;
            w0[0] = (int)(hb ? r2 : r0);  w0[1] = (int)(hb ? r3 : r1);
            w0[2] = (int)(hb ? r0 : r2);  w0[3] = (int)(hb ? r1 : r3);
            w1[0] = (int)(hb ? r6 : r4);  w1[1] = (int)(hb ? r7 : r5);
            w1[2] = (int)(hb ? r4 : r6);  w1[3] = (int)(hb ? r5 : r7);
            pa0[u] = __builtin_bit_cast(bf16x8, w0);
            pa1[u] = __builtin_bit_cast(bf16x8, w1);
        }

        // ---- PV; bv shared across u
        __builtin_amdgcn_s_setprio(1);
        #pragma unroll
        for (int n = 0; n < 8; ++n) {
            bf16x8 bv0 = read_frag64(lvc, n * 16 + r15, g * 8);
            oacc[0][n] = mfma_bf16(pa0[0], bv0, oacc[0][n]);
            oacc[1][n] = mfma_bf16(pa0[1], bv0, oacc[1][n]);
            bf16x8 bv1 = read_frag64(lvc, n * 16 + r15, 32 + g * 8);
            oacc[0][n] = mfma_bf16(pa1[0], bv1, oacc[0][n]);
            oacc[1][n] = mfma_bf16(pa1[1], bv1, oacc[1][n]);
        }
        __builtin_amdgcn_s_setprio(0);

        asm volatile("s_waitcnt vmcnt(0)" ::: "memory");
        __builtin_amdgcn_s_barrier();
    }

    // ---- store PARTIAL L (f32) and PARTIAL O (bf16, unnormalized)
    #pragma unroll
    for (int u = 0; u < 2; ++u) {
        float L = Lsum[u];
        L += __shfl_xor(L, 16);
        L += __shfl_xor(L, 32);
        int qrow = qb * 128 + w * 32 + u * 16;
        if (g == 0)
            Lp[((size_t)sp * NH + h) * SEQ + qrow + r15] = L;

        #pragma unroll
        for (int n = 0; n < 8; ++n) {
            int col = h * HD + n * 16 + r15;
            int rowb = qrow + g * 4;
            #pragma unroll
            for (int r = 0; r < 4; ++r)
                Op[(size_t)sp * SEQ * DM + (size_t)(rowb + r) * DM + col] = (bf16_t)oacc[u][n][r];
        }
    }
}

extern "C" void kernel_launch(void* const* d_in, const int* in_sizes, int n_in,
                              void* d_out, int out_size, void* d_ws, size_t ws_size,
                              hipStream_t stream)
{
    const float* x    = (const float*)d_in[0];
    const float* fcos = (const float*)d_in[1];
    const float* fsin = (const float*)d_in[2];
    const float* Wq   = (const float*)d_in[3];
    const float* Wk   = (const float*)d_in[4];
    const float* Wv   = (const float*)d_in[5];
    const float* Wo   = (const float*)d_in[6];
    float* out = (float*)d_out;

    const size_t NE = (size_t)DM * SEQ;
    bf16_t* ws  = (bf16_t*)d_ws;
    bf16_t* xb  = ws;            // slot 0; reused as Op[0] after qkv_pipe
    bf16_t* wqb = ws + 1 * NE;   // slot 1; reused as Op[1]
    bf16_t* wkb = ws + 2 * NE;   // slot 2
    bf16_t* wvb = ws + 3 * NE;   // slot 3
    bf16_t* qr  = ws + 5 * NE;
    bf16_t* kr  = ws + 6 * NE;
    bf16_t* vt  = ws + 7 * NE;
    bf16_t* op  = ws;                       // partial O: 2 slabs (slots 0-1)
    float*  lp  = (float*)(ws + 9 * NE);    // partial L: 2*16*2048 f32 = 256KB

    hipLaunchKernelGGL(cvt5, dim3(4096, 4), dim3(256), 0, stream,
                       x, Wq, Wk, Wv, (const float*)nullptr,
                       xb, wqb, wkb, wvb, (bf16_t*)nullptr);

    hipLaunchKernelGGL(qkv_pipe, dim3(24, 8), dim3(512), 0, stream,
                       xb, wqb, wkb, wvb, qr, kr, vt, fcos, fsin);

    hipLaunchKernelGGL(attn_k6, dim3(16, 16, 2), dim3(256), 0, stream,
                       qr, kr, vt, op, lp);

    hipLaunchKernelGGL(gemm_fin, dim3(16, 32), dim3(256), 0, stream,
                       op, lp, Wo, out);
}

// Round 13
// 166.085 us; speedup vs baseline: 1.6648x; 1.6648x over previous
//
#include <hip/hip_runtime.h>
#include <hip/hip_bf16.h>
#include <math.h>

#define SEQ 2048
#define DM  2048
#define NH  16
#define HD  128
#define SCALE 0.08838834764831845f

typedef __bf16 bf16_t;
typedef __bf16 bf16x8 __attribute__((ext_vector_type(8)));
typedef __bf16 bf16x4 __attribute__((ext_vector_type(4)));
typedef float  f32x4  __attribute__((ext_vector_type(4)));
typedef int    i32x4  __attribute__((ext_vector_type(4)));

typedef const __attribute__((address_space(1))) void* gas_ptr;
typedef __attribute__((address_space(3))) void* las_ptr;

__device__ __forceinline__ void gload_lds16(const void* g, void* l) {
    __builtin_amdgcn_global_load_lds((gas_ptr)g, (las_ptr)l, 16, 0, 0);
}

__device__ __forceinline__ f32x4 mfma_bf16(bf16x8 a, bf16x8 b, f32x4 c) {
    return __builtin_amdgcn_mfma_f32_16x16x32_bf16(a, b, c, 0, 0, 0);
}

__device__ __forceinline__ unsigned cvtpk_bf16(float lo, float hi) {
    unsigned d;
    asm("v_cvt_pk_bf16_f32 %0, %1, %2" : "=v"(d) : "v"(lo), "v"(hi));
    return d;
}

// LDS tile with 64 bf16 per row (128B): chunk (16B) XOR-swizzled by row&7
__device__ __forceinline__ bf16x8 read_frag64(const bf16_t* lds, int row, int k) {
    int chunk = (k >> 3) ^ (row & 7);
    return *(const bf16x8*)(lds + row * 64 + chunk * 8);
}
// LDS tile with 128 bf16 per row (256B): low 3 chunk bits swizzled
__device__ __forceinline__ bf16x8 read_frag128(const bf16_t* lds, int row, int k) {
    int chunk = k >> 3;
    chunk = (chunk & 8) | ((chunk ^ row) & 7);
    return *(const bf16x8*)(lds + row * 128 + chunk * 8);
}
// K-slab layout [256 rows][32 bf16], 16B slot-swizzled: phys j = kj ^ ((row>>1)&3)
__device__ __forceinline__ bf16x8 read_slab(const bf16_t* sl, int row, int g) {
    int j = g ^ ((row >> 1) & 3);
    return *(const bf16x8*)(sl + row * 32 + j * 8);
}

// ---------------- fp32 -> bf16 conversion (5 arrays of 2048*2048) -------------
__global__ __launch_bounds__(256) void cvt5(
    const float* __restrict__ s0, const float* __restrict__ s1,
    const float* __restrict__ s2, const float* __restrict__ s3,
    const float* __restrict__ s4,
    bf16_t* __restrict__ d0, bf16_t* __restrict__ d1, bf16_t* __restrict__ d2,
    bf16_t* __restrict__ d3, bf16_t* __restrict__ d4)
{
    int which = blockIdx.y;
    const float* s; bf16_t* d;
    switch (which) {
        case 0: s = s0; d = d0; break;
        case 1: s = s1; d = d1; break;
        case 2: s = s2; d = d2; break;
        case 3: s = s3; d = d3; break;
        default: s = s4; d = d4; break;
    }
    size_t idx = ((size_t)blockIdx.x * 256 + threadIdx.x) * 4;
    float4 v = *(const float4*)(s + idx);
    bf16x4 o = { (bf16_t)v.x, (bf16_t)v.y, (bf16_t)v.z, (bf16_t)v.w };
    *(bf16x4*)(d + idx) = o;
}

// ---------------- pipelined QKV GEMM: 256x256, BK=64, merged double-phases ---
// grid (24 bny, 8 bm): XCD = linear%8 = bny%8 -> 3 B-panels L2-resident per XCD
#define BARX() asm volatile("s_barrier" ::: "memory")
#define VMW8 asm volatile("s_waitcnt vmcnt(8)" ::: "memory")
#define VMW4 asm volatile("s_waitcnt vmcnt(4)" ::: "memory")
#define VMW0 asm volatile("s_waitcnt vmcnt(0)" ::: "memory")
#define NOGATE

__global__ __launch_bounds__(512, 2) void qkv_pipe(
    const bf16_t* __restrict__ A,
    const bf16_t* __restrict__ B0, const bf16_t* __restrict__ B1,
    const bf16_t* __restrict__ B2,
    bf16_t* __restrict__ Oq, bf16_t* __restrict__ Ok, bf16_t* __restrict__ Ov,
    const float* __restrict__ fcos, const float* __restrict__ fsin)
{
    __shared__ bf16_t lds[65536];   // 128 KB

    const int tid = threadIdx.x;
    const int lane = tid & 63;
    const int w = tid >> 6;
    const int wm = w >> 2;           // 0..1
    const int wn = w & 3;            // 0..3
    const int g4 = lane >> 4, r15 = lane & 15;

    const int bm = blockIdx.y;       // 0..7
    const int bny = blockIdx.x;      // 0..23
    const int sel = bny >> 3;
    const int bnl = bny & 7;
    const bf16_t* Bp = (sel == 0) ? B0 : (sel == 1) ? B1 : B2;

    const size_t arow0 = (size_t)bm * 256;
    const size_t brow0 = (size_t)bnl * 256;

    const int row0 = tid >> 2;                    // c0 row (c1 row = row0+128)
    const int kj0  = (tid & 3) ^ ((row0 >> 1) & 3);
    const bf16_t* pA = A  + (arow0 + row0) * DM + kj0 * 8;
    const bf16_t* pB = Bp + (brow0 + row0) * DM + kj0 * 8;
    char* ldsb = (char*)lds;
    const int off0 = tid * 16;
    const int off1 = 8192 + tid * 16;

    #define STAGE_HT(S) do { if ((S) < 128) {                                   \
        const int T_ = (S) >> 2, a_ = (S) & 3;                                  \
        const int ko_ = T_ * 64 + ((a_ >> 1) << 5);                             \
        char* dst_ = ldsb + (((T_ & 1) << 16) | ((a_ & 1) << 15) | ((a_ >> 1) << 14)); \
        const bf16_t* s0_ = (a_ & 1) ? pB : pA;                                 \
        gload_lds16(s0_ + ko_, dst_ + off0);                                    \
        gload_lds16(s0_ + 128 * DM + ko_, dst_ + off1);                         \
    } } while (0)

    const bf16_t* b0A0 = lds;
    const bf16_t* b0A1 = lds + 8192;
    const bf16_t* b0B0 = lds + 16384;
    const bf16_t* b0B1 = lds + 24576;
    const bf16_t* b1A0 = lds + 32768;
    const bf16_t* b1A1 = lds + 40960;
    const bf16_t* b1B0 = lds + 49152;
    const bf16_t* b1B1 = lds + 57344;

    f32x4 acc[8][4] = {};

    #define PHASE2(ASL, BSL, S1, S2, GATE)                                      \
    {                                                                           \
        GATE;                                                                   \
        _Pragma("unroll")                                                       \
        for (int k = 0; k < 8; ++k)                                             \
            af[k] = read_slab((ASL), wm * 128 + k * 16 + r15, g4);              \
        _Pragma("unroll")                                                       \
        for (int n = 0; n < 4; ++n)                                             \
            bfr[n] = read_slab((BSL), wn * 64 + n * 16 + r15, g4);              \
        STAGE_HT(S1);                                                           \
        STAGE_HT(S2);                                                           \
        BARX();                                                                 \
        __builtin_amdgcn_s_setprio(1);                                          \
        _Pragma("unroll")                                                       \
        for (int k = 0; k < 8; ++k)                                             \
            _Pragma("unroll")                                                   \
            for (int n = 0; n < 4; ++n)                                         \
                acc[k][n] = mfma_bf16(af[k], bfr[n], acc[k][n]);                \
        __builtin_amdgcn_s_setprio(0);                                          \
        BARX();                                                                 \
    }

    STAGE_HT(0); STAGE_HT(1); STAGE_HT(2); STAGE_HT(3); STAGE_HT(4); STAGE_HT(5);
    VMW8;
    BARX();

    for (int i = 0; i < 15; ++i) {
        const int s0 = 6 + i * 8;
        bf16x8 af[8], bfr[4];
        PHASE2(b0A0, b0B0, s0 + 0, s0 + 1, VMW8)
        PHASE2(b0A1, b0B1, s0 + 2, s0 + 3, VMW8)
        PHASE2(b1A0, b1B0, s0 + 4, s0 + 5, VMW8)
        PHASE2(b1A1, b1B1, s0 + 6, s0 + 7, VMW8)
    }
    {   // final iter: stages 126,127 real, rest no-op; drain 8 -> 4 -> 0
        bf16x8 af[8], bfr[4];
        PHASE2(b0A0, b0B0, 126, 127, VMW8)
        PHASE2(b0A1, b0B1, 200, 200, VMW8)
        PHASE2(b1A0, b1B0, 200, 200, VMW4)
        PHASE2(b1A1, b1B1, 200, 200, VMW0)
    }
    #undef PHASE2
    #undef STAGE_HT

    const int r0 = bm * 256 + wm * 128;
    const int c0 = bnl * 256 + wn * 64;

    if (sel == 2) {
        #pragma unroll
        for (int m = 0; m < 8; ++m) {
            int rowb = r0 + m * 16 + g4 * 4;
            #pragma unroll
            for (int n = 0; n < 4; ++n) {
                int col = c0 + n * 16 + r15;
                bf16x4 pk = { (bf16_t)acc[m][n][0], (bf16_t)acc[m][n][1],
                              (bf16_t)acc[m][n][2], (bf16_t)acc[m][n][3] };
                *(bf16x4*)&Ov[(size_t)col * SEQ + rowb] = pk;
            }
        }
    } else {
        bf16_t* dst = (sel == 0) ? Oq : Ok;
        #pragma unroll
        for (int m = 0; m < 8; ++m) {
            int rowb = r0 + m * 16 + g4 * 4;
            #pragma unroll
            for (int n = 0; n < 4; ++n) {
                int col = c0 + n * 16 + r15;
                int f = (col & (HD - 1)) >> 1;
                float sgn = (col & 1) ? 1.0f : -1.0f;
                #pragma unroll
                for (int r = 0; r < 4; ++r) {
                    float mine = acc[m][n][r];
                    float other = __shfl_xor(mine, 1);
                    float cc = fcos[(rowb + r) * (HD / 2) + f];
                    float ss = fsin[(rowb + r) * (HD / 2) + f];
                    float o = mine * cc + sgn * other * ss;
                    dst[(size_t)(rowb + r) * DM + col] = (bf16_t)o;
                }
            }
        }
    }
}

// ---------------- final projection GEMM (128x64 tile, 2 blocks/CU) -----------
__global__ __launch_bounds__(256) void gemm_fin(
    const bf16_t* __restrict__ A, const bf16_t* __restrict__ B0,
    float* __restrict__ Of)
{
    __shared__ bf16_t lA[128 * 64];
    __shared__ bf16_t lB[64 * 64];

    const int tid = threadIdx.x;
    const int lane = tid & 63;
    const int w = tid >> 6;
    const int wm = w >> 1, wn = w & 1;
    const int g = lane >> 4, r15 = lane & 15;

    const int bm = blockIdx.x;   // 0..15
    const int bn = blockIdx.y;   // 0..31

    f32x4 acc[4][2] = {};

    const size_t arow0 = (size_t)bm * 128;
    const size_t brow0 = (size_t)bn * 64;

    for (int kt = 0; kt < DM / 64; ++kt) {
        const int k0 = kt * 64;
        #pragma unroll
        for (int i = 0; i < 4; ++i) {
            int c = i * 256 + tid;
            int row = c >> 3;
            int ck = (c ^ row) & 7;
            const bf16_t* ga = A + (arow0 + row) * DM + k0 + ck * 8;
            gload_lds16(ga, (char*)lA + (i * 256 + w * 64) * 16);
        }
        #pragma unroll
        for (int i = 0; i < 2; ++i) {
            int c = i * 256 + tid;
            int row = c >> 3;
            int ck = (c ^ row) & 7;
            const bf16_t* gb = B0 + (brow0 + row) * DM + k0 + ck * 8;
            gload_lds16(gb, (char*)lB + (i * 256 + w * 64) * 16);
        }
        __syncthreads();
        #pragma unroll
        for (int kk = 0; kk < 2; ++kk) {
            bf16x8 af[4], bfr[2];
            #pragma unroll
            for (int m = 0; m < 4; ++m)
                af[m] = read_frag64(lA, wm * 64 + m * 16 + r15, kk * 32 + g * 8);
            #pragma unroll
            for (int n = 0; n < 2; ++n)
                bfr[n] = read_frag64(lB, wn * 32 + n * 16 + r15, kk * 32 + g * 8);
            #pragma unroll
            for (int m = 0; m < 4; ++m)
                #pragma unroll
                for (int n = 0; n < 2; ++n)
                    acc[m][n] = mfma_bf16(af[m], bfr[n], acc[m][n]);
        }
        __syncthreads();
    }

    const int r0 = bm * 128 + wm * 64;
    const int c0 = bn * 64 + wn * 32;
    #pragma unroll
    for (int m = 0; m < 4; ++m) {
        int rowb = r0 + m * 16 + g * 4;
        #pragma unroll
        for (int n = 0; n < 2; ++n) {
            int col = c0 + n * 16 + r15;
            #pragma unroll
            for (int r = 0; r < 4; ++r)
                Of[(size_t)(rowb + r) * DM + col] = acc[m][n][r];
        }
    }
}

// ---------------- attention v7: QBLK=128, key-split 2, 2 blocks/CU -----------
// grid (16 qb, 16 h, 2 sp) = 512 blocks, 256 thr = 4 waves, wave = 32 q-rows
// (u in {0,1}). Each block handles keys [sp*1024, sp*1024+1024) = 16 j-iters,
// writes PARTIAL O (bf16) + PARTIAL L (f32); attn_cmb sums (associative since
// the reference normalizes per 64-key block - no online rescale needed).
__global__ __launch_bounds__(256, 2) void attn_k6(
    const bf16_t* __restrict__ Q, const bf16_t* __restrict__ Kb,
    const bf16_t* __restrict__ Vt, bf16_t* __restrict__ Op,
    float* __restrict__ Lp)
{
    __shared__ bf16_t lk[2 * 64 * 128];   // K tiles (double buffer)
    __shared__ bf16_t lv[2 * 128 * 64];   // V^T tiles (double buffer)

    const int tid = threadIdx.x;          // 0..255
    const int lane = tid & 63;
    const int w = tid >> 6;               // 0..3: q-rows w*32 .. w*32+31
    const int g = lane >> 4, r15 = lane & 15;
    const int qb = blockIdx.x;            // 0..15
    const int h = blockIdx.y;             // 0..15
    const int sp = blockIdx.z;            // 0..1
    const int j0 = sp * 16;

    const int lo = g & 1, hb = g >> 1;
    const int e_src = (lo << 5) + r15;
    const int o_src = e_src + 16;
    const int sA = hb ? o_src : e_src;
    const int sB = hb ? e_src : o_src;

    // Q fragments: qf[u][ks] for q = qb*128 + w*32 + u*16 + r15
    bf16x8 qf[2][4];
    #pragma unroll
    for (int u = 0; u < 2; ++u) {
        const bf16_t* qrow = Q + (size_t)(qb * 128 + w * 32 + u * 16 + r15) * DM + h * HD + g * 8;
        #pragma unroll
        for (int ks = 0; ks < 4; ++ks)
            qf[u][ks] = *(const bf16x8*)(qrow + ks * 32);
    }

    f32x4 oacc[2][8] = {};
    float Lsum[2] = {0.f, 0.f};

    #define STAGE_KV(JJ, BUF)                                                     \
    {                                                                             \
        _Pragma("unroll")                                                         \
        for (int i = 0; i < 4; ++i) {                                             \
            int c = i * 256 + tid;                                                \
            int row = c >> 4, ckl = c & 15;                                       \
            int ck = (ckl & 8) | ((ckl ^ row) & 7);                               \
            const bf16_t* gk = Kb + (size_t)((JJ) * 64 + row) * DM + h * HD + ck * 8; \
            gload_lds16(gk, (char*)lk + (BUF) * 16384 + (i * 256 + w * 64) * 16); \
        }                                                                         \
        _Pragma("unroll")                                                         \
        for (int i = 0; i < 4; ++i) {                                             \
            int c = i * 256 + tid;                                                \
            int row = c >> 3;                                                     \
            int ck = (c ^ row) & 7;                                               \
            const bf16_t* gv = Vt + (size_t)(h * HD + row) * SEQ + (JJ) * 64 + ck * 8; \
            gload_lds16(gv, (char*)lv + (BUF) * 16384 + (i * 256 + w * 64) * 16); \
        }                                                                         \
    }

    STAGE_KV(j0, 0);
    asm volatile("s_waitcnt vmcnt(0)" ::: "memory");
    __builtin_amdgcn_s_barrier();

    for (int jj = 0; jj < 16; ++jj) {
        const int cur = jj & 1;
        const bf16_t* lkc = lk + cur * 8192;
        const bf16_t* lvc = lv + cur * 8192;
        if (jj < 15) STAGE_KV(j0 + jj + 1, cur ^ 1);

        // ---- QK^T swapped; kf shared across u
        f32x4 sacc[2][4] = {};
        __builtin_amdgcn_s_setprio(1);
        #pragma unroll
        for (int ks = 0; ks < 4; ++ks) {
            #pragma unroll
            for (int n = 0; n < 4; ++n) {
                bf16x8 kf = read_frag128(lkc, n * 16 + r15, ks * 32 + g * 8);
                sacc[0][n] = mfma_bf16(kf, qf[0][ks], sacc[0][n]);
                sacc[1][n] = mfma_bf16(kf, qf[1][ks], sacc[1][n]);
            }
        }
        __builtin_amdgcn_s_setprio(0);

        bf16x8 pa0[2], pa1[2];
        #pragma unroll
        for (int u = 0; u < 2; ++u) {
            float mx0 = fmaxf(fmaxf(sacc[u][0][0], sacc[u][0][1]), fmaxf(sacc[u][0][2], sacc[u][0][3]));
            float mx1 = fmaxf(fmaxf(sacc[u][1][0], sacc[u][1][1]), fmaxf(sacc[u][1][2], sacc[u][1][3]));
            float mx2 = fmaxf(fmaxf(sacc[u][2][0], sacc[u][2][1]), fmaxf(sacc[u][2][2], sacc[u][2][3]));
            float mx3 = fmaxf(fmaxf(sacc[u][3][0], sacc[u][3][1]), fmaxf(sacc[u][3][2], sacc[u][3][3]));
            float mx = fmaxf(fmaxf(mx0, mx1), fmaxf(mx2, mx3));
            mx = fmaxf(mx, __shfl_xor(mx, 16));
            mx = fmaxf(mx, __shfl_xor(mx, 32));

            float p[4][4];
            float ls = 0.f;
            #pragma unroll
            for (int n = 0; n < 4; ++n)
                #pragma unroll
                for (int r = 0; r < 4; ++r) {
                    float pv = __expf((sacc[u][n][r] - mx) * SCALE);
                    p[n][r] = pv;
                    ls += pv;
                }
            Lsum[u] += ls;

            unsigned D00 = cvtpk_bf16(p[0][0], p[0][1]), D01 = cvtpk_bf16(p[0][2], p[0][3]);
            unsigned D10 = cvtpk_bf16(p[1][0], p[1][1]), D11 = cvtpk_bf16(p[1][2], p[1][3]);
            unsigned D20 = cvtpk_bf16(p[2][0], p[2][1]), D21 = cvtpk_bf16(p[2][2], p[2][3]);
            unsigned D30 = cvtpk_bf16(p[3][0], p[3][1]), D31 = cvtpk_bf16(p[3][2], p[3][3]);

            unsigned r0 = __shfl((int)(lo ? D10 : D00), sA);
            unsigned r1 = __shfl((int)(lo ? D11 : D01), sA);
            unsigned r2 = __shfl((int)(lo ? D00 : D10), sB);
            unsigned r3 = __shfl((int)(lo ? D01 : D11), sB);
            unsigned r4 = __shfl((int)(lo ? D30 : D20), sA);
            unsigned r5 = __shfl((int)(lo ? D31 : D21), sA);
            unsigned r6 = __shfl((int)(lo ? D20 : D30), sB);
            unsigned r7 = __shfl((int)(lo ? D21 : D31), sB);
            i32x4 w0, w1;
            w0[0] = (int)(hb ? r2 : r0);  w0[1] = (int)(hb ? r3 : r1);
            w0[2] = (int)(hb ? r0 : r2);  w0[3] = (int)(hb ? r1 : r3);
            w1[0] = (int)(hb ? r6 : r4);  w1[1] = (int)(hb ? r7 : r5);
            w1[2] = (int)(hb ? r4 : r6);  w1[3] = (int)(hb ? r5 : r7);
            pa0[u] = __builtin_bit_cast(bf16x8, w0);
            pa1[u] = __builtin_bit_cast(bf16x8, w1);
        }

        // ---- PV; bv shared across u
        __builtin_amdgcn_s_setprio(1);
        #pragma unroll
        for (int n = 0; n < 8; ++n) {
            bf16x8 bv0 = read_frag64(lvc, n * 16 + r15, g * 8);
            oacc[0][n] = mfma_bf16(pa0[0], bv0, oacc[0][n]);
            oacc[1][n] = mfma_bf16(pa0[1], bv0, oacc[1][n]);
            bf16x8 bv1 = read_frag64(lvc, n * 16 + r15, 32 + g * 8);
            oacc[0][n] = mfma_bf16(pa1[0], bv1, oacc[0][n]);
            oacc[1][n] = mfma_bf16(pa1[1], bv1, oacc[1][n]);
        }
        __builtin_amdgcn_s_setprio(0);

        asm volatile("s_waitcnt vmcnt(0)" ::: "memory");
        __builtin_amdgcn_s_barrier();
    }

    // ---- store PARTIAL L (f32) and PARTIAL O (bf16, unnormalized)
    #pragma unroll
    for (int u = 0; u < 2; ++u) {
        float L = Lsum[u];
        L += __shfl_xor(L, 16);
        L += __shfl_xor(L, 32);
        int qrow = qb * 128 + w * 32 + u * 16;
        if (g == 0)
            Lp[((size_t)sp * NH + h) * SEQ + qrow + r15] = L;

        #pragma unroll
        for (int n = 0; n < 8; ++n) {
            int col = h * HD + n * 16 + r15;
            int rowb = qrow + g * 4;
            #pragma unroll
            for (int r = 0; r < 4; ++r)
                Op[(size_t)sp * SEQ * DM + (size_t)(rowb + r) * DM + col] = (bf16_t)oacc[u][n][r];
        }
    }
}

// ---------------- combine partials: O = (sum Op) / (sum L + eps) -------------
__global__ __launch_bounds__(256) void attn_cmb(
    const bf16_t* __restrict__ Op, const float* __restrict__ Lp,
    bf16_t* __restrict__ Ob)
{
    const int row = blockIdx.x;
    const int c0 = threadIdx.x * 8;
    const int h = c0 >> 7;

    float L = 1e-6f;
    #pragma unroll
    for (int s = 0; s < 2; ++s)
        L += Lp[((size_t)s * NH + h) * SEQ + row];

    float acc[8] = {};
    #pragma unroll
    for (int s = 0; s < 2; ++s) {
        bf16x8 v = *(const bf16x8*)(Op + (size_t)s * SEQ * DM + (size_t)row * DM + c0);
        #pragma unroll
        for (int j = 0; j < 8; ++j)
            acc[j] += (float)v[j];
    }
    float inv = 1.0f / L;
    bf16x8 o;
    #pragma unroll
    for (int j = 0; j < 8; ++j)
        o[j] = (bf16_t)(acc[j] * inv);
    *(bf16x8*)(Ob + (size_t)row * DM + c0) = o;
}

extern "C" void kernel_launch(void* const* d_in, const int* in_sizes, int n_in,
                              void* d_out, int out_size, void* d_ws, size_t ws_size,
                              hipStream_t stream)
{
    const float* x    = (const float*)d_in[0];
    const float* fcos = (const float*)d_in[1];
    const float* fsin = (const float*)d_in[2];
    const float* Wq   = (const float*)d_in[3];
    const float* Wk   = (const float*)d_in[4];
    const float* Wv   = (const float*)d_in[5];
    const float* Wo   = (const float*)d_in[6];
    float* out = (float*)d_out;

    const size_t NE = (size_t)DM * SEQ;
    bf16_t* ws  = (bf16_t*)d_ws;
    bf16_t* xb  = ws;            // slot 0; reused as Op[0] after qkv_pipe
    bf16_t* wqb = ws + 1 * NE;   // slot 1; reused as Op[1]
    bf16_t* wkb = ws + 2 * NE;   // slot 2
    bf16_t* wvb = ws + 3 * NE;   // slot 3
    bf16_t* wob = ws + 4 * NE;   // slot 4 (needed by gemm_fin at the end)
    bf16_t* qr  = ws + 5 * NE;
    bf16_t* kr  = ws + 6 * NE;
    bf16_t* vt  = ws + 7 * NE;
    bf16_t* ob  = ws + 8 * NE;
    bf16_t* op  = ws;                       // partial O: 2 slabs (slots 0-1)
    float*  lp  = (float*)(ws + 9 * NE);    // partial L: 2*16*2048 f32 = 256KB

    hipLaunchKernelGGL(cvt5, dim3(4096, 5), dim3(256), 0, stream,
                       x, Wq, Wk, Wv, Wo, xb, wqb, wkb, wvb, wob);

    hipLaunchKernelGGL(qkv_pipe, dim3(24, 8), dim3(512), 0, stream,
                       xb, wqb, wkb, wvb, qr, kr, vt, fcos, fsin);

    hipLaunchKernelGGL(attn_k6, dim3(16, 16, 2), dim3(256), 0, stream,
                       qr, kr, vt, op, lp);

    hipLaunchKernelGGL(attn_cmb, dim3(2048), dim3(256), 0, stream,
                       op, lp, ob);

    hipLaunchKernelGGL(gemm_fin, dim3(16, 32), dim3(256), 0, stream,
                       ob, wob, out);
}